// Round 1
// baseline (648.594 us; speedup 1.0000x reference)
//
#include <hip/hip_runtime.h>

// ---------------------------------------------------------------------------
// PYG_GCN: y = relu(x@W_in+b_in) -> GCNConv(W_gcn,b_gcn) -> relu -> @W_cls+b_cls
// N=50000 nodes, E=600000 edges, D=128, 40 classes, fp32.
// ---------------------------------------------------------------------------

__global__ __launch_bounds__(256) void k_deg_init(float* deg, int n) {
  int i = blockIdx.x * 256 + threadIdx.x;
  if (i < n) deg[i] = 1.0f;  // self-loop contributes 1 to in-degree
}

__global__ __launch_bounds__(256) void k_deg_count(const int* __restrict__ col,
                                                   float* deg, int E, int n) {
  int e = blockIdx.x * 256 + threadIdx.x;
  if (e < E) {
    int c = col[e];
    if ((unsigned)c < (unsigned)n) atomicAdd(&deg[c], 1.0f);
  }
}

__global__ __launch_bounds__(256) void k_deg_fin(float* deg, int n) {
  int i = blockIdx.x * 256 + threadIdx.x;
  if (i < n) deg[i] = rsqrtf(deg[i]);  // deg >= 1 always (self-loop)
}

// ---------------------------------------------------------------------------
// GEMM: O[r][c] = act(sum_k A[r][k]*W[k][c] + bias[c]), K=Ncols=128.
// 64 rows/block, 256 threads, each thread 4 rows x 8 cols (two float4 col
// groups at tc*4 and 64+tc*4 so Ws reads are 2-way-max on banks).
// ---------------------------------------------------------------------------
template<bool RELU, bool BIAS>
__global__ __launch_bounds__(256) void k_gemm128(const float* __restrict__ A,
                                                 const float* __restrict__ W,
                                                 const float* __restrict__ bias,
                                                 float* __restrict__ O, int nrows) {
  __shared__ float xs[64][36];    // pad 36: row-dist 4 -> bank dist 16, 2-way max
  __shared__ float Ws[32][128];
  const int tid = threadIdx.x;
  const int row0 = blockIdx.x * 64;
  const int tc = tid & 15;   // 16 col groups
  const int tr = tid >> 4;   // 16 row groups of 4 rows

  float acc[4][8];
#pragma unroll
  for (int i = 0; i < 4; ++i)
#pragma unroll
    for (int j = 0; j < 8; ++j) acc[i][j] = 0.f;

  for (int k0 = 0; k0 < 128; k0 += 32) {
    // load x tile 64x32 (512 float4, coalesced)
#pragma unroll
    for (int q = 0; q < 2; ++q) {
      int idx = tid + 256 * q;
      int r = idx >> 3, cg = idx & 7;
      float4 v = make_float4(0.f, 0.f, 0.f, 0.f);
      if (row0 + r < nrows)
        v = *(const float4*)&A[(size_t)(row0 + r) * 128 + k0 + cg * 4];
      *(float4*)&xs[r][cg * 4] = v;
    }
    // load W tile 32x128 (1024 float4, coalesced)
#pragma unroll
    for (int q = 0; q < 4; ++q) {
      int f = tid + 256 * q;
      int r = f >> 5, c4 = f & 31;
      *(float4*)&Ws[r][c4 * 4] = *(const float4*)&W[(size_t)(k0 + r) * 128 + c4 * 4];
    }
    __syncthreads();
#pragma unroll
    for (int kk = 0; kk < 32; ++kk) {
      float xv[4];
#pragma unroll
      for (int i = 0; i < 4; ++i) xv[i] = xs[tr * 4 + i][kk];
      float4 w0 = *(float4*)&Ws[kk][tc * 4];
      float4 w1 = *(float4*)&Ws[kk][64 + tc * 4];
      float wv[8] = {w0.x, w0.y, w0.z, w0.w, w1.x, w1.y, w1.z, w1.w};
#pragma unroll
      for (int i = 0; i < 4; ++i)
#pragma unroll
        for (int j = 0; j < 8; ++j)
          acc[i][j] = fmaf(xv[i], wv[j], acc[i][j]);
    }
    __syncthreads();
  }

  float bv[8];
#pragma unroll
  for (int j = 0; j < 4; ++j) {
    bv[j]     = BIAS ? bias[tc * 4 + j] : 0.f;
    bv[j + 4] = BIAS ? bias[64 + tc * 4 + j] : 0.f;
  }
#pragma unroll
  for (int i = 0; i < 4; ++i) {
    int r = row0 + tr * 4 + i;
    if (r < nrows) {
      float o[8];
#pragma unroll
      for (int j = 0; j < 8; ++j) {
        float v = acc[i][j] + bv[j];
        o[j] = RELU ? fmaxf(v, 0.f) : v;
      }
      *(float4*)&O[(size_t)r * 128 + tc * 4]      = make_float4(o[0], o[1], o[2], o[3]);
      *(float4*)&O[(size_t)r * 128 + 64 + tc * 4] = make_float4(o[4], o[5], o[6], o[7]);
    }
  }
}

// ---------------------------------------------------------------------------
// Scatter: one wave per edge; lane l handles 2 floats of the 128-wide row.
// g[col] += dinv[row]*dinv[col] * xw[row]
// ---------------------------------------------------------------------------
__global__ __launch_bounds__(256) void k_scatter(const int* __restrict__ row,
                                                 const int* __restrict__ col,
                                                 const float* __restrict__ dinv,
                                                 const float* __restrict__ xw,
                                                 float* __restrict__ g,
                                                 int E, int n) {
  int wid = blockIdx.x * 4 + (threadIdx.x >> 6);
  int lane = threadIdx.x & 63;
  if (wid >= E) return;
  int r = row[wid], c = col[wid];
  if ((unsigned)r >= (unsigned)n || (unsigned)c >= (unsigned)n) return;
  float w = dinv[r] * dinv[c];
  float2 v = *(const float2*)&xw[(size_t)r * 128 + lane * 2];
  atomicAdd(&g[(size_t)c * 128 + lane * 2],     w * v.x);
  atomicAdd(&g[(size_t)c * 128 + lane * 2 + 1], w * v.y);
}

// ---------------------------------------------------------------------------
// Output layer: t = relu(gsc + dinv^2*xw + b_gcn); out = t @ W_cls + b_cls
// 32 rows/block; t and W_cls staged in LDS. Self-loop folded in here.
// ---------------------------------------------------------------------------
__global__ __launch_bounds__(256) void k_out(const float* __restrict__ gsc,
                                             const float* __restrict__ xw,
                                             const float* __restrict__ dinv,
                                             const float* __restrict__ b_gcn,
                                             const float* __restrict__ Wc,
                                             const float* __restrict__ b_cls,
                                             float* __restrict__ out, int nrows) {
  __shared__ float ts[32][132];
  __shared__ float Wcs[128 * 40];
  const int tid = threadIdx.x;
  const int row0 = blockIdx.x * 32;

  // stage W_cls (5120 floats = 1280 float4)
#pragma unroll
  for (int q = 0; q < 5; ++q) {
    int f = tid + 256 * q;
    *(float4*)&Wcs[f * 4] = *(const float4*)&Wc[f * 4];
  }
  // compute t rows
  {
    int r = tid >> 3;
    int c0 = (tid & 7) * 16;
    int row = row0 + r;
    float sn = 0.f;
    if (row < nrows) { float dv = dinv[row]; sn = dv * dv; }
#pragma unroll
    for (int q = 0; q < 4; ++q) {
      int c = c0 + q * 4;
      float4 gv = make_float4(0.f, 0.f, 0.f, 0.f);
      float4 xv = gv;
      if (row < nrows) {
        gv = *(const float4*)&gsc[(size_t)row * 128 + c];
        xv = *(const float4*)&xw[(size_t)row * 128 + c];
      }
      float4 bv = *(const float4*)&b_gcn[c];
      float4 t;
      t.x = fmaxf(gv.x + sn * xv.x + bv.x, 0.f);
      t.y = fmaxf(gv.y + sn * xv.y + bv.y, 0.f);
      t.z = fmaxf(gv.z + sn * xv.z + bv.z, 0.f);
      t.w = fmaxf(gv.w + sn * xv.w + bv.w, 0.f);
      *(float4*)&ts[r][c] = t;
    }
  }
  __syncthreads();
  // 32*40 = 1280 outputs, 5 per thread
#pragma unroll
  for (int q = 0; q < 5; ++q) {
    int o = tid + 256 * q;
    int r = o / 40, c = o - r * 40;
    int row = row0 + r;
    if (row < nrows) {
      float acc = b_cls[c];
#pragma unroll 8
      for (int k = 0; k < 128; ++k)
        acc = fmaf(ts[r][k], Wcs[k * 40 + c], acc);
      out[(size_t)row * 40 + c] = acc;
    }
  }
}

extern "C" void kernel_launch(void* const* d_in, const int* in_sizes, int n_in,
                              void* d_out, int out_size, void* d_ws, size_t ws_size,
                              hipStream_t stream) {
  const float* x     = (const float*)d_in[0];
  const int*   ei    = (const int*)d_in[1];
  const float* W_in  = (const float*)d_in[2];
  const float* b_in  = (const float*)d_in[3];
  const float* W_gcn = (const float*)d_in[4];
  const float* b_gcn = (const float*)d_in[5];
  const float* W_cls = (const float*)d_in[6];
  const float* b_cls = (const float*)d_in[7];
  float* out = (float*)d_out;

  const int N = in_sizes[0] / 128;
  const int E = in_sizes[1] / 2;
  const int* row = ei;
  const int* col = ei + E;

  float* h    = (float*)d_ws;               // N*128 floats; reused as g after GEMM2
  float* xw   = h + (size_t)N * 128;        // N*128 floats
  float* dinv = xw + (size_t)N * 128;       // N floats (deg -> dinv in place)

  // layer 1: h = relu(x @ W_in + b_in)
  k_gemm128<true, true><<<(N + 63) / 64, 256, 0, stream>>>(x, W_in, b_in, h, N);

  // degree + normalization
  k_deg_init<<<(N + 255) / 256, 256, 0, stream>>>(dinv, N);
  k_deg_count<<<(E + 255) / 256, 256, 0, stream>>>(col, dinv, E, N);
  k_deg_fin<<<(N + 255) / 256, 256, 0, stream>>>(dinv, N);

  // xw = h @ W_gcn  (bias applied post-aggregation in k_out)
  k_gemm128<false, false><<<(N + 63) / 64, 256, 0, stream>>>(h, W_gcn, nullptr, xw, N);

  // zero the aggregation buffer (reuse h), then scatter edges
  hipMemsetAsync(h, 0, (size_t)N * 128 * sizeof(float), stream);
  k_scatter<<<(E + 3) / 4, 256, 0, stream>>>(row, col, dinv, xw, h, E, N);

  // out = relu(g + dinv^2*xw + b_gcn) @ W_cls + b_cls   (self-loop folded in)
  k_out<<<(N + 31) / 32, 256, 0, stream>>>(h, xw, dinv, b_gcn, W_cls, b_cls, out, N);
}

// Round 2
// 217.119 us; speedup vs baseline: 2.9873x; 2.9873x over previous
//
#include <hip/hip_runtime.h>

// ---------------------------------------------------------------------------
// PYG_GCN: y = relu(x@W_in+b_in) -> GCNConv(W_gcn,b_gcn) -> relu -> @W_cls+b_cls
// N=50000, E=600000, D=128, C=40, fp32.
// Strategy: counting-sort edges by dst col -> CSR gather (no float atomics).
// norm separability: g[c] = dinv[c]*(sum_e dinv[r]*xw[r] + dinv[c]*xw[c]) + b
// ---------------------------------------------------------------------------

// ---------------- degree histogram / normalization -------------------------
__global__ __launch_bounds__(256) void k_hist(const int* __restrict__ col,
                                              int* __restrict__ C, int E, int n) {
  int e = blockIdx.x * 256 + threadIdx.x;
  if (e < E) {
    int c = col[e];
    if ((unsigned)c < (unsigned)n) atomicAdd(&C[c], 1);
  }
}

__global__ __launch_bounds__(256) void k_dinv(const int* __restrict__ C,
                                              float* __restrict__ dinv, int n) {
  int i = blockIdx.x * 256 + threadIdx.x;
  if (i < n) dinv[i] = rsqrtf((float)C[i] + 1.0f);  // +1 self-loop
}

// ---------------- exclusive scan over N counters (in place) ----------------
__global__ __launch_bounds__(256) void k_scan1(int* __restrict__ P,
                                               int* __restrict__ aux, int n) {
  __shared__ int sd[256];
  const int tid = threadIdx.x;
  const int i0 = blockIdx.x * 1024 + tid * 4;
  int4 v = make_int4(0, 0, 0, 0);
  if (i0 + 3 < n) v = *(const int4*)&P[i0];
  else {
    if (i0 < n) v.x = P[i0];
    if (i0 + 1 < n) v.y = P[i0 + 1];
    if (i0 + 2 < n) v.z = P[i0 + 2];
  }
  const int s = v.x + v.y + v.z + v.w;
  sd[tid] = s;
  __syncthreads();
  for (int off = 1; off < 256; off <<= 1) {
    int u = (tid >= off) ? sd[tid - off] : 0;
    __syncthreads();
    sd[tid] += u;
    __syncthreads();
  }
  if (tid == 255) aux[blockIdx.x] = sd[255];
  const int excl = sd[tid] - s;
  int4 o;
  o.x = excl; o.y = o.x + v.x; o.z = o.y + v.y; o.w = o.z + v.z;
  if (i0 + 3 < n) *(int4*)&P[i0] = o;
  else {
    if (i0 < n) P[i0] = o.x;
    if (i0 + 1 < n) P[i0 + 1] = o.y;
    if (i0 + 2 < n) P[i0 + 2] = o.z;
  }
}

__global__ __launch_bounds__(64) void k_scan2(int* __restrict__ aux, int nblk) {
  const int lane = threadIdx.x;
  int v = (lane < nblk) ? aux[lane] : 0;
  int inc = v;
  for (int off = 1; off < 64; off <<= 1) {
    int u = __shfl_up(inc, off);
    if (lane >= off) inc += u;
  }
  if (lane < nblk) aux[lane] = inc - v;  // exclusive
}

__global__ __launch_bounds__(256) void k_scan3(int* __restrict__ P,
                                               const int* __restrict__ aux, int n) {
  const int i0 = blockIdx.x * 1024 + threadIdx.x * 4;
  const int a = aux[blockIdx.x];
  if (i0 + 3 < n) {
    int4 v = *(int4*)&P[i0];
    v.x += a; v.y += a; v.z += a; v.w += a;
    *(int4*)&P[i0] = v;
  } else {
    if (i0 < n) P[i0] += a;
    if (i0 + 1 < n) P[i0 + 1] += a;
    if (i0 + 2 < n) P[i0 + 2] += a;
  }
}

// ---------------- placement: bucket edges by col ---------------------------
// After this kernel, P[c] = start[c+1]; node c's segment = [P[c-1], P[c]).
__global__ __launch_bounds__(256) void k_place(const int* __restrict__ row,
                                               const int* __restrict__ col,
                                               int* __restrict__ P,
                                               int* __restrict__ srcrow,
                                               int E, int n) {
  int e = blockIdx.x * 256 + threadIdx.x;
  if (e < E) {
    int c = col[e];
    if ((unsigned)c < (unsigned)n) {
      int pos = atomicAdd(&P[c], 1);
      srcrow[pos] = row[e];
    }
  }
}

// ---------------------------------------------------------------------------
// GEMM 128x128: O[r][c] = post(sum_k A[r][k]*W[k][c])
// post: +bias (BIAS), relu (RELU), *scale[r] (SCALE)
// ---------------------------------------------------------------------------
template<bool RELU, bool BIAS, bool SCALE>
__global__ __launch_bounds__(256) void k_gemm128(const float* __restrict__ A,
                                                 const float* __restrict__ W,
                                                 const float* __restrict__ bias,
                                                 const float* __restrict__ scale,
                                                 float* __restrict__ O, int nrows) {
  __shared__ float xs[64][36];
  __shared__ float Ws[32][128];
  const int tid = threadIdx.x;
  const int row0 = blockIdx.x * 64;
  const int tc = tid & 15;
  const int tr = tid >> 4;

  float acc[4][8];
#pragma unroll
  for (int i = 0; i < 4; ++i)
#pragma unroll
    for (int j = 0; j < 8; ++j) acc[i][j] = 0.f;

  for (int k0 = 0; k0 < 128; k0 += 32) {
#pragma unroll
    for (int q = 0; q < 2; ++q) {
      int idx = tid + 256 * q;
      int r = idx >> 3, cg = idx & 7;
      float4 v = make_float4(0.f, 0.f, 0.f, 0.f);
      if (row0 + r < nrows)
        v = *(const float4*)&A[(size_t)(row0 + r) * 128 + k0 + cg * 4];
      *(float4*)&xs[r][cg * 4] = v;
    }
#pragma unroll
    for (int q = 0; q < 4; ++q) {
      int f = tid + 256 * q;
      int r = f >> 5, c4 = f & 31;
      *(float4*)&Ws[r][c4 * 4] = *(const float4*)&W[(size_t)(k0 + r) * 128 + c4 * 4];
    }
    __syncthreads();
#pragma unroll
    for (int kk = 0; kk < 32; ++kk) {
      float xv[4];
#pragma unroll
      for (int i = 0; i < 4; ++i) xv[i] = xs[tr * 4 + i][kk];
      float4 w0 = *(float4*)&Ws[kk][tc * 4];
      float4 w1 = *(float4*)&Ws[kk][64 + tc * 4];
      float wv[8] = {w0.x, w0.y, w0.z, w0.w, w1.x, w1.y, w1.z, w1.w};
#pragma unroll
      for (int i = 0; i < 4; ++i)
#pragma unroll
        for (int j = 0; j < 8; ++j)
          acc[i][j] = fmaf(xv[i], wv[j], acc[i][j]);
    }
    __syncthreads();
  }

  float bv[8];
#pragma unroll
  for (int j = 0; j < 4; ++j) {
    bv[j]     = BIAS ? bias[tc * 4 + j] : 0.f;
    bv[j + 4] = BIAS ? bias[64 + tc * 4 + j] : 0.f;
  }
#pragma unroll
  for (int i = 0; i < 4; ++i) {
    int r = row0 + tr * 4 + i;
    if (r < nrows) {
      float sc = SCALE ? scale[r] : 1.f;
      float o[8];
#pragma unroll
      for (int j = 0; j < 8; ++j) {
        float v = acc[i][j] + bv[j];
        if (RELU) v = fmaxf(v, 0.f);
        if (SCALE) v *= sc;
        o[j] = v;
      }
      *(float4*)&O[(size_t)r * 128 + tc * 4]      = make_float4(o[0], o[1], o[2], o[3]);
      *(float4*)&O[(size_t)r * 128 + 64 + tc * 4] = make_float4(o[4], o[5], o[6], o[7]);
    }
  }
}

// ---------------------------------------------------------------------------
// Aggregate: one wave per node. t[c] = relu(dinv[c]*(sum xws[r] + xws[c]) + b)
// ---------------------------------------------------------------------------
__global__ __launch_bounds__(256) void k_agg(const int* __restrict__ P,
                                             const int* __restrict__ srcrow,
                                             const float* __restrict__ xws,
                                             const float* __restrict__ dinv,
                                             const float* __restrict__ b_gcn,
                                             float* __restrict__ t, int n) {
  const int c = blockIdx.x * 4 + (threadIdx.x >> 6);
  if (c >= n) return;
  const int lane = threadIdx.x & 63;
  const int begin = (c == 0) ? 0 : P[c - 1];
  const int end = P[c];

  float2 acc = *(const float2*)&xws[(size_t)c * 128 + lane * 2];  // self term
  int e = begin;
  for (; e + 4 <= end; e += 4) {
    int r0 = srcrow[e], r1 = srcrow[e + 1], r2 = srcrow[e + 2], r3 = srcrow[e + 3];
    float2 v0 = *(const float2*)&xws[(size_t)r0 * 128 + lane * 2];
    float2 v1 = *(const float2*)&xws[(size_t)r1 * 128 + lane * 2];
    float2 v2 = *(const float2*)&xws[(size_t)r2 * 128 + lane * 2];
    float2 v3 = *(const float2*)&xws[(size_t)r3 * 128 + lane * 2];
    acc.x += (v0.x + v1.x) + (v2.x + v3.x);
    acc.y += (v0.y + v1.y) + (v2.y + v3.y);
  }
  for (; e < end; ++e) {
    int r = srcrow[e];
    float2 v = *(const float2*)&xws[(size_t)r * 128 + lane * 2];
    acc.x += v.x; acc.y += v.y;
  }
  const float dc = dinv[c];
  float2 b = *(const float2*)&b_gcn[lane * 2];
  float2 tv;
  tv.x = fmaxf(fmaf(dc, acc.x, b.x), 0.f);
  tv.y = fmaxf(fmaf(dc, acc.y, b.y), 0.f);
  *(float2*)&t[(size_t)c * 128 + lane * 2] = tv;
}

// ---------------------------------------------------------------------------
// Output layer: out = t @ W_cls + b_cls   (t already relu'd + biased)
// ---------------------------------------------------------------------------
__global__ __launch_bounds__(256) void k_out(const float* __restrict__ t,
                                             const float* __restrict__ Wc,
                                             const float* __restrict__ bc,
                                             float* __restrict__ out, int nrows) {
  __shared__ float ts[32][132];
  __shared__ float Wcs[128 * 40];
  const int tid = threadIdx.x;
  const int row0 = blockIdx.x * 32;

#pragma unroll
  for (int q = 0; q < 5; ++q) {
    int f = (tid + 256 * q) * 4;
    *(float4*)&Wcs[f] = *(const float4*)&Wc[f];
  }
#pragma unroll
  for (int q = 0; q < 4; ++q) {
    int idx = tid + 256 * q;      // [0,1024) float4s
    int r = idx >> 5, c4 = idx & 31;
    float4 v = make_float4(0.f, 0.f, 0.f, 0.f);
    if (row0 + r < nrows) v = *(const float4*)&t[(size_t)(row0 + r) * 128 + c4 * 4];
    *(float4*)&ts[r][c4 * 4] = v;
  }
  __syncthreads();

#pragma unroll
  for (int q = 0; q < 5; ++q) {
    int o = tid + 256 * q;        // [0,1280)
    int r = o / 40, c = o - r * 40;
    int rr = row0 + r;
    if (rr < nrows) {
      float acc = bc[c];
#pragma unroll 8
      for (int k = 0; k < 128; ++k)
        acc = fmaf(ts[r][k], Wcs[k * 40 + c], acc);
      out[(size_t)rr * 40 + c] = acc;
    }
  }
}

extern "C" void kernel_launch(void* const* d_in, const int* in_sizes, int n_in,
                              void* d_out, int out_size, void* d_ws, size_t ws_size,
                              hipStream_t stream) {
  const float* x     = (const float*)d_in[0];
  const int*   ei    = (const int*)d_in[1];
  const float* W_in  = (const float*)d_in[2];
  const float* b_in  = (const float*)d_in[3];
  const float* W_gcn = (const float*)d_in[4];
  const float* b_gcn = (const float*)d_in[5];
  const float* W_cls = (const float*)d_in[6];
  const float* b_cls = (const float*)d_in[7];
  float* out = (float*)d_out;

  const int N = in_sizes[0] / 128;
  const int E = in_sizes[1] / 2;
  const int* row = ei;
  const int* col = ei + E;
  const int nblk = (N + 1023) / 1024;

  // workspace: h/t (N*128), xws (N*128), P (N ints)  -> 51.6 MB
  float* h   = (float*)d_ws;                 // GEMM1 out / reused as t
  float* xws = h + (size_t)N * 128;          // scaled GEMM2 out
  int*   P   = (int*)(xws + (size_t)N * 128);
  // scratch parked in d_out (8 MB, fully overwritten by k_out at the end):
  int*   srcrow = (int*)d_out;               // E ints
  float* dinv   = (float*)d_out + E;         // N floats
  int*   aux    = (int*)d_out + E + N;       // nblk ints

  // layer 1: h = relu(x @ W_in + b_in)
  k_gemm128<true, true, false><<<(N + 63) / 64, 256, 0, stream>>>(x, W_in, b_in, nullptr, h, N);

  // degree histogram -> dinv -> exclusive scan (in place) -> CSR placement
  hipMemsetAsync(P, 0, (size_t)N * sizeof(int), stream);
  k_hist<<<(E + 255) / 256, 256, 0, stream>>>(col, P, E, N);
  k_dinv<<<(N + 255) / 256, 256, 0, stream>>>(P, dinv, N);
  k_scan1<<<nblk, 256, 0, stream>>>(P, aux, N);
  k_scan2<<<1, 64, 0, stream>>>(aux, nblk);
  k_scan3<<<nblk, 256, 0, stream>>>(P, aux, N);
  k_place<<<(E + 255) / 256, 256, 0, stream>>>(row, col, P, srcrow, E, N);

  // xws = dinv[r] * (h @ W_gcn)
  k_gemm128<false, false, true><<<(N + 63) / 64, 256, 0, stream>>>(h, W_gcn, nullptr, dinv, xws, N);

  // t = relu(dinv[c]*(sum_{e->c} xws[r] + xws[c]) + b_gcn), writes into h
  k_agg<<<(N + 3) / 4, 256, 0, stream>>>(P, srcrow, xws, dinv, b_gcn, h, N);

  // out = t @ W_cls + b_cls
  k_out<<<(N + 31) / 32, 256, 0, stream>>>(h, W_cls, b_cls, out, N);
}

// Round 3
// 162.307 us; speedup vs baseline: 3.9961x; 1.3377x over previous
//
#include <hip/hip_runtime.h>

// ---------------------------------------------------------------------------
// PYG_GCN: y = relu(x@W_in+b_in) -> GCNConv(W_gcn,b_gcn) -> relu -> @W_cls+b_cls
// N=50000, E=600000, D=128, C=40.
// This round: bf16 MFMA GEMMs (16x16x32), bf16 gather in k_agg.
// ---------------------------------------------------------------------------

typedef __bf16 bf16x8 __attribute__((ext_vector_type(8)));
typedef float f32x4 __attribute__((ext_vector_type(4)));

__device__ __forceinline__ ushort f2b(float f) {  // fp32 -> bf16 RNE
  uint u = __float_as_uint(f);
  return (ushort)((u + 0x7FFFu + ((u >> 16) & 1u)) >> 16);
}
__device__ __forceinline__ float b2f_lo(uint u) { return __uint_as_float(u << 16); }
__device__ __forceinline__ float b2f_hi(uint u) { return __uint_as_float(u & 0xFFFF0000u); }

// ---------------- prep: transpose+convert weights to bf16 col-major --------
// Ti[c][k]=W_in[k][c]; Tg[c][k]=W_gcn[k][c]; Tc[c][k]=W_cls[k][c] (48 rows, pad 0)
__global__ __launch_bounds__(256) void k_prep(const float* __restrict__ Wi,
                                              const float* __restrict__ Wg,
                                              const float* __restrict__ Wc,
                                              ushort* __restrict__ Ti,
                                              ushort* __restrict__ Tg,
                                              ushort* __restrict__ Tc) {
  int idx = blockIdx.x * 256 + threadIdx.x;
  if (idx < 16384) {
    int c = idx >> 7, k = idx & 127;
    Ti[c * 128 + k] = f2b(Wi[k * 128 + c]);
  } else if (idx < 32768) {
    int j = idx - 16384;
    int c = j >> 7, k = j & 127;
    Tg[c * 128 + k] = f2b(Wg[k * 128 + c]);
  } else if (idx < 38912) {
    int j = idx - 32768;
    int c = j >> 7, k = j & 127;
    Tc[c * 128 + k] = (c < 40) ? f2b(Wc[k * 40 + c]) : (ushort)0;
  }
}

// ---------------- degree histogram / normalization -------------------------
__global__ __launch_bounds__(256) void k_hist(const int* __restrict__ col,
                                              int* __restrict__ C, int E, int n) {
  int e = blockIdx.x * 256 + threadIdx.x;
  if (e < E) {
    int c = col[e];
    if ((unsigned)c < (unsigned)n) atomicAdd(&C[c], 1);
  }
}

__global__ __launch_bounds__(256) void k_dinv(const int* __restrict__ C,
                                              float* __restrict__ dinv, int n) {
  int i = blockIdx.x * 256 + threadIdx.x;
  if (i < n) dinv[i] = rsqrtf((float)C[i] + 1.0f);  // +1 self-loop
}

// ---------------- exclusive scan over N counters (in place) ----------------
__global__ __launch_bounds__(256) void k_scan1(int* __restrict__ P,
                                               int* __restrict__ aux, int n) {
  __shared__ int sd[256];
  const int tid = threadIdx.x;
  const int i0 = blockIdx.x * 1024 + tid * 4;
  int4 v = make_int4(0, 0, 0, 0);
  if (i0 + 3 < n) v = *(const int4*)&P[i0];
  else {
    if (i0 < n) v.x = P[i0];
    if (i0 + 1 < n) v.y = P[i0 + 1];
    if (i0 + 2 < n) v.z = P[i0 + 2];
  }
  const int s = v.x + v.y + v.z + v.w;
  sd[tid] = s;
  __syncthreads();
  for (int off = 1; off < 256; off <<= 1) {
    int u = (tid >= off) ? sd[tid - off] : 0;
    __syncthreads();
    sd[tid] += u;
    __syncthreads();
  }
  if (tid == 255) aux[blockIdx.x] = sd[255];
  const int excl = sd[tid] - s;
  int4 o;
  o.x = excl; o.y = o.x + v.x; o.z = o.y + v.y; o.w = o.z + v.z;
  if (i0 + 3 < n) *(int4*)&P[i0] = o;
  else {
    if (i0 < n) P[i0] = o.x;
    if (i0 + 1 < n) P[i0 + 1] = o.y;
    if (i0 + 2 < n) P[i0 + 2] = o.z;
  }
}

__global__ __launch_bounds__(64) void k_scan2(int* __restrict__ aux, int nblk) {
  const int lane = threadIdx.x;
  int v = (lane < nblk) ? aux[lane] : 0;
  int inc = v;
  for (int off = 1; off < 64; off <<= 1) {
    int u = __shfl_up(inc, off);
    if (lane >= off) inc += u;
  }
  if (lane < nblk) aux[lane] = inc - v;  // exclusive
}

__global__ __launch_bounds__(256) void k_scan3(int* __restrict__ P,
                                               const int* __restrict__ aux, int n) {
  const int i0 = blockIdx.x * 1024 + threadIdx.x * 4;
  const int a = aux[blockIdx.x];
  if (i0 + 3 < n) {
    int4 v = *(int4*)&P[i0];
    v.x += a; v.y += a; v.z += a; v.w += a;
    *(int4*)&P[i0] = v;
  } else {
    if (i0 < n) P[i0] += a;
    if (i0 + 1 < n) P[i0 + 1] += a;
    if (i0 + 2 < n) P[i0 + 2] += a;
  }
}

// ---------------- placement: bucket edges by col ---------------------------
// After this kernel, P[c] = start[c+1]; node c's segment = [P[c-1], P[c]).
__global__ __launch_bounds__(256) void k_place(const int* __restrict__ row,
                                               const int* __restrict__ col,
                                               int* __restrict__ P,
                                               int* __restrict__ srcrow,
                                               int E, int n) {
  int e = blockIdx.x * 256 + threadIdx.x;
  if (e < E) {
    int c = col[e];
    if ((unsigned)c < (unsigned)n) {
      int pos = atomicAdd(&P[c], 1);
      srcrow[pos] = row[e];
    }
  }
}

// ---------------------------------------------------------------------------
// MFMA GEMM, 64 rows/block, 128 cols, K=128. Wt is bf16 col-major [128][128].
// A is fp32 (ABF16=0) or bf16 (ABF16=1), row-major [nrows][128].
// O (bf16) = post(A @ W): +bias, relu, *scale[row].
// LDS rows padded to 136 ushorts (272 B) -> conflict-free ds_read_b128.
// ---------------------------------------------------------------------------
template<bool RELU, bool BIAS, bool SCALE, bool ABF16>
__global__ __launch_bounds__(256) void k_gemm_mfma(const void* __restrict__ Ap,
                                                   const ushort* __restrict__ Wt,
                                                   const float* __restrict__ bias,
                                                   const float* __restrict__ scale,
                                                   ushort* __restrict__ O, int nrows) {
  __shared__ ushort As[64][136];
  __shared__ ushort Bs[128][136];
  const int tid = threadIdx.x;
  const int row0 = blockIdx.x * 64;

  // stage Wt: 16384 bf16 = 2048 x 16B chunks
#pragma unroll
  for (int q = 0; q < 8; ++q) {
    int f = tid + 256 * q;
    int r = f >> 4, cw = f & 15;
    *(uint4*)&Bs[r][cw * 8] = *(const uint4*)&Wt[r * 128 + cw * 8];
  }
  // stage A tile 64x128
  if (ABF16) {
    const ushort* A = (const ushort*)Ap;
#pragma unroll
    for (int q = 0; q < 4; ++q) {
      int f = tid + 256 * q;
      int r = f >> 4, cw = f & 15;
      uint4 v = make_uint4(0u, 0u, 0u, 0u);
      if (row0 + r < nrows) v = *(const uint4*)&A[(size_t)(row0 + r) * 128 + cw * 8];
      *(uint4*)&As[r][cw * 8] = v;
    }
  } else {
    const float* A = (const float*)Ap;
#pragma unroll
    for (int q = 0; q < 8; ++q) {
      int f = tid + 256 * q;
      int r = f >> 5, kc = f & 31;
      float4 v = make_float4(0.f, 0.f, 0.f, 0.f);
      if (row0 + r < nrows) v = *(const float4*)&A[(size_t)(row0 + r) * 128 + kc * 4];
      ushort4 o;
      o.x = f2b(v.x); o.y = f2b(v.y); o.z = f2b(v.z); o.w = f2b(v.w);
      *(ushort4*)&As[r][kc * 4] = o;
    }
  }
  __syncthreads();

  const int wid = tid >> 6, lane = tid & 63;
  const int fr = lane & 15;   // frag row (A) / col (B/D)
  const int fg = lane >> 4;   // k-group (input) / row-group (D)

  f32x4 acc[8];
#pragma unroll
  for (int n = 0; n < 8; ++n) acc[n] = (f32x4){0.f, 0.f, 0.f, 0.f};

#pragma unroll
  for (int ks = 0; ks < 4; ++ks) {
    const int kb = ks * 32 + fg * 8;
    bf16x8 a = *(const bf16x8*)&As[wid * 16 + fr][kb];
#pragma unroll
    for (int n = 0; n < 8; ++n) {
      bf16x8 b = *(const bf16x8*)&Bs[n * 16 + fr][kb];
      acc[n] = __builtin_amdgcn_mfma_f32_16x16x32_bf16(a, b, acc[n], 0, 0, 0);
    }
  }

  const int r0 = row0 + wid * 16 + fg * 4;
#pragma unroll
  for (int n = 0; n < 8; ++n) {
    const int cn = n * 16 + fr;
    const float bv = BIAS ? bias[cn] : 0.f;
#pragma unroll
    for (int i = 0; i < 4; ++i) {
      const int rr = r0 + i;
      if (rr < nrows) {
        float v = acc[n][i] + bv;
        if (RELU) v = fmaxf(v, 0.f);
        if (SCALE) v *= scale[rr];
        O[(size_t)rr * 128 + cn] = f2b(v);
      }
    }
  }
}

// ---------------------------------------------------------------------------
// Aggregate (bf16 gather): t[c] = relu(dinv[c]*(sum xws[r] + xws[c]) + b_gcn)
// One wave per node; lane owns cols {2*lane, 2*lane+1} (one uint load/edge).
// ---------------------------------------------------------------------------
__global__ __launch_bounds__(256) void k_agg(const int* __restrict__ P,
                                             const int* __restrict__ srcrow,
                                             const ushort* __restrict__ xws,
                                             const float* __restrict__ dinv,
                                             const float* __restrict__ b_gcn,
                                             ushort* __restrict__ t, int n) {
  const int c = blockIdx.x * 4 + (threadIdx.x >> 6);
  if (c >= n) return;
  const int lane = threadIdx.x & 63;
  const int begin = (c == 0) ? 0 : P[c - 1];
  const int end = P[c];
  const size_t off = (size_t)lane * 2;

  uint s = *(const uint*)&xws[(size_t)c * 128 + off];  // self term
  float ax = b2f_lo(s), ay = b2f_hi(s);
  int e = begin;
  for (; e + 4 <= end; e += 4) {
    int r0 = srcrow[e], r1 = srcrow[e + 1], r2 = srcrow[e + 2], r3 = srcrow[e + 3];
    uint v0 = *(const uint*)&xws[(size_t)r0 * 128 + off];
    uint v1 = *(const uint*)&xws[(size_t)r1 * 128 + off];
    uint v2 = *(const uint*)&xws[(size_t)r2 * 128 + off];
    uint v3 = *(const uint*)&xws[(size_t)r3 * 128 + off];
    ax += (b2f_lo(v0) + b2f_lo(v1)) + (b2f_lo(v2) + b2f_lo(v3));
    ay += (b2f_hi(v0) + b2f_hi(v1)) + (b2f_hi(v2) + b2f_hi(v3));
  }
  for (; e < end; ++e) {
    uint v = *(const uint*)&xws[(size_t)srcrow[e] * 128 + off];
    ax += b2f_lo(v);
    ay += b2f_hi(v);
  }
  const float dc = dinv[c];
  const float2 b = *(const float2*)&b_gcn[lane * 2];
  ushort2 o;
  o.x = f2b(fmaxf(fmaf(dc, ax, b.x), 0.f));
  o.y = f2b(fmaxf(fmaf(dc, ay, b.y), 0.f));
  *(ushort2*)&t[(size_t)c * 128 + off] = o;
}

// ---------------------------------------------------------------------------
// Output layer MFMA: out[fp32] = t[bf16] @ W_cls + b_cls. N padded 40->48.
// ---------------------------------------------------------------------------
__global__ __launch_bounds__(256) void k_out_mfma(const ushort* __restrict__ t,
                                                  const ushort* __restrict__ Wtc,
                                                  const float* __restrict__ bc,
                                                  float* __restrict__ out, int nrows) {
  __shared__ ushort As[64][136];
  __shared__ ushort Bs[48][136];
  const int tid = threadIdx.x;
  const int row0 = blockIdx.x * 64;

#pragma unroll
  for (int q = 0; q < 3; ++q) {
    int f = tid + 256 * q;  // 768 chunks
    int r = f >> 4, cw = f & 15;
    *(uint4*)&Bs[r][cw * 8] = *(const uint4*)&Wtc[r * 128 + cw * 8];
  }
#pragma unroll
  for (int q = 0; q < 4; ++q) {
    int f = tid + 256 * q;
    int r = f >> 4, cw = f & 15;
    uint4 v = make_uint4(0u, 0u, 0u, 0u);
    if (row0 + r < nrows) v = *(const uint4*)&t[(size_t)(row0 + r) * 128 + cw * 8];
    *(uint4*)&As[r][cw * 8] = v;
  }
  __syncthreads();

  const int wid = tid >> 6, lane = tid & 63;
  const int fr = lane & 15, fg = lane >> 4;

  f32x4 acc[3];
#pragma unroll
  for (int n = 0; n < 3; ++n) acc[n] = (f32x4){0.f, 0.f, 0.f, 0.f};

#pragma unroll
  for (int ks = 0; ks < 4; ++ks) {
    const int kb = ks * 32 + fg * 8;
    bf16x8 a = *(const bf16x8*)&As[wid * 16 + fr][kb];
#pragma unroll
    for (int n = 0; n < 3; ++n) {
      bf16x8 b = *(const bf16x8*)&Bs[n * 16 + fr][kb];
      acc[n] = __builtin_amdgcn_mfma_f32_16x16x32_bf16(a, b, acc[n], 0, 0, 0);
    }
  }

  const int r0 = row0 + wid * 16 + fg * 4;
#pragma unroll
  for (int n = 0; n < 3; ++n) {
    const int cn = n * 16 + fr;
    if (cn < 40) {
      const float bv = bc[cn];
#pragma unroll
      for (int i = 0; i < 4; ++i) {
        const int rr = r0 + i;
        if (rr < nrows) out[(size_t)rr * 40 + cn] = acc[n][i] + bv;
      }
    }
  }
}

extern "C" void kernel_launch(void* const* d_in, const int* in_sizes, int n_in,
                              void* d_out, int out_size, void* d_ws, size_t ws_size,
                              hipStream_t stream) {
  const float* x     = (const float*)d_in[0];
  const int*   ei    = (const int*)d_in[1];
  const float* W_in  = (const float*)d_in[2];
  const float* b_in  = (const float*)d_in[3];
  const float* W_gcn = (const float*)d_in[4];
  const float* b_gcn = (const float*)d_in[5];
  const float* W_cls = (const float*)d_in[6];
  const float* b_cls = (const float*)d_in[7];
  float* out = (float*)d_out;

  const int N = in_sizes[0] / 128;
  const int E = in_sizes[1] / 2;
  const int* row = ei;
  const int* col = ei + E;
  const int nblk = (N + 1023) / 1024;

  // workspace: h/t bf16 (N*128), xws bf16 (N*128), P (N int), Wt buffers
  ushort* h   = (ushort*)d_ws;               // GEMM1 out; reused as t after GEMM2
  ushort* xws = h + (size_t)N * 128;
  int*    P   = (int*)(xws + (size_t)N * 128);
  ushort* Wti = (ushort*)(P + N);
  ushort* Wtg = Wti + 128 * 128;
  ushort* Wtc = Wtg + 128 * 128;             // 48 x 128 (zero-padded)
  // scratch parked in d_out (fully overwritten by k_out_mfma at the end):
  int*    srcrow = (int*)d_out;              // E ints
  float*  dinv   = (float*)d_out + E;        // N floats
  int*    aux    = (int*)d_out + E + N;      // nblk ints

  // weight transpose+convert
  k_prep<<<152, 256, 0, stream>>>(W_in, W_gcn, W_cls, Wti, Wtg, Wtc);

  // degree histogram -> dinv -> exclusive scan (in place) -> CSR placement
  hipMemsetAsync(P, 0, (size_t)N * sizeof(int), stream);
  k_hist<<<(E + 255) / 256, 256, 0, stream>>>(col, P, E, N);
  k_dinv<<<(N + 255) / 256, 256, 0, stream>>>(P, dinv, N);
  k_scan1<<<nblk, 256, 0, stream>>>(P, aux, N);
  k_scan2<<<1, 64, 0, stream>>>(aux, nblk);
  k_scan3<<<nblk, 256, 0, stream>>>(P, aux, N);
  k_place<<<(E + 255) / 256, 256, 0, stream>>>(row, col, P, srcrow, E, N);

  // h = relu(x @ W_in + b_in)          [bf16 out]
  k_gemm_mfma<true, true, false, false>
      <<<(N + 63) / 64, 256, 0, stream>>>(x, Wti, b_in, nullptr, h, N);

  // xws = dinv[r] * (h @ W_gcn)        [bf16 out]
  k_gemm_mfma<false, false, true, true>
      <<<(N + 63) / 64, 256, 0, stream>>>(h, Wtg, nullptr, dinv, xws, N);

  // t = relu(dinv[c]*(sum_{e->c} xws[r] + xws[c]) + b_gcn)   (t -> h buffer)
  k_agg<<<(N + 3) / 4, 256, 0, stream>>>(P, srcrow, xws, dinv, b_gcn, h, N);

  // out = t @ W_cls + b_cls
  k_out_mfma<<<(N + 63) / 64, 256, 0, stream>>>(h, Wtc, b_cls, out, N);
}